// Round 3
// baseline (2654.327 us; speedup 1.0000x reference)
//
#include <hip/hip_runtime.h>
#include <hip/hip_bf16.h>
#include <math.h>

typedef __hip_bfloat16 bf16;
typedef unsigned short u16;
typedef unsigned int   u32;

#define NTOK 100352   // 32 * 56 * 56
#define QSCALE 0.17677669529663687f

__device__ __forceinline__ float b2f(u16 u) { return __uint_as_float(((u32)u) << 16); }

// ---------------- fp32 -> bf16 conversion (weights) ----------------
__global__ __launch_bounds__(256)
void cvt_kernel(const float* __restrict__ src, bf16* __restrict__ dst, int n)
{
  const int i = blockIdx.x * 256 + threadIdx.x;
  if (i < n) dst[i] = __float2bfloat16(src[i]);
}

// ---------------- pos-bias MLP + rel_bias table (1 block) ----------------
__device__ __forceinline__ void ln16_relu(float* cur, const float* g, const float* b) {
  float mu = 0.f;
#pragma unroll
  for (int j = 0; j < 16; ++j) mu += cur[j];
  mu *= (1.f / 16.f);
  float var = 0.f;
#pragma unroll
  for (int j = 0; j < 16; ++j) { float d = cur[j] - mu; var += d * d; }
  var *= (1.f / 16.f);
  const float r = rsqrtf(var + 1e-5f);
#pragma unroll
  for (int j = 0; j < 16; ++j) {
    float y = (cur[j] - mu) * r * g[j] + b[j];
    cur[j] = fmaxf(y, 0.f);
  }
}

__global__ __launch_bounds__(256)
void pos_kernel(const float* __restrict__ ppw, const float* __restrict__ ppb,
                const float* __restrict__ g1, const float* __restrict__ lb1,
                const float* __restrict__ w1, const float* __restrict__ b1,
                const float* __restrict__ g2, const float* __restrict__ lb2,
                const float* __restrict__ w2, const float* __restrict__ b2,
                const float* __restrict__ g3, const float* __restrict__ lb3,
                const float* __restrict__ w3, const float* __restrict__ b3,
                float* __restrict__ rel_bias)
{
  __shared__ float pos_s[169 * 8];
  const int t = threadIdx.x;
  if (t < 169) {
    float cur[16], nxt[16];
    const float bh = (float)(t / 13 - 6), bw = (float)(t % 13 - 6);
#pragma unroll
    for (int j = 0; j < 16; ++j)
      cur[j] = bh * ppw[j] + bw * ppw[16 + j] + ppb[j];
    ln16_relu(cur, g1, lb1);
    for (int j = 0; j < 16; ++j) nxt[j] = b1[j];
    for (int k = 0; k < 16; ++k) { float a = cur[k]; for (int j = 0; j < 16; ++j) nxt[j] += a * w1[k * 16 + j]; }
    for (int j = 0; j < 16; ++j) cur[j] = nxt[j];
    ln16_relu(cur, g2, lb2);
    for (int j = 0; j < 16; ++j) nxt[j] = b2[j];
    for (int k = 0; k < 16; ++k) { float a = cur[k]; for (int j = 0; j < 16; ++j) nxt[j] += a * w2[k * 16 + j]; }
    for (int j = 0; j < 16; ++j) cur[j] = nxt[j];
    ln16_relu(cur, g3, lb3);
    for (int h = 0; h < 8; ++h) {
      float s = b3[h];
      for (int k = 0; k < 16; ++k) s += cur[k] * w3[k * 8 + h];
      pos_s[t * 8 + h] = s;
    }
  }
  __syncthreads();
  for (int e = t; e < 8 * 2401; e += 256) {
    const int h = e / 2401, ij = e % 2401, i = ij / 49, j = ij % 49;
    const int dh = i / 7 - j / 7 + 6, dw = i % 7 - j % 7 + 6;
    rel_bias[e] = pos_s[(dh * 13 + dw) * 8 + h];
  }
}

// ---------------- LayerNorm over C=256 (fp32 in, bf16 out) ----------------
__global__ __launch_bounds__(256)
void ln_kernel(const float* __restrict__ xin,
               const float* __restrict__ g, const float* __restrict__ b,
               bf16* __restrict__ out)
{
  const int tok = blockIdx.x, c = threadIdx.x;
  const float xv = xin[(size_t)tok * 256 + c];
  __shared__ float red[256];
  red[c] = xv; __syncthreads();
#pragma unroll
  for (int s = 128; s > 0; s >>= 1) { if (c < s) red[c] += red[c + s]; __syncthreads(); }
  const float mu = red[0] * (1.f / 256.f);
  __syncthreads();
  const float d = xv - mu;
  red[c] = d * d; __syncthreads();
#pragma unroll
  for (int s = 128; s > 0; s >>= 1) { if (c < s) red[c] += red[c + s]; __syncthreads(); }
  const float rstd = rsqrtf(red[0] * (1.f / 256.f) + 1e-5f);
  const float y = d * rstd * g[c] + b[c];
  out[(size_t)tok * 256 + c] = __float2bfloat16(y);
}

// ---------------- tiled GEMM (bf16 in, fp32 accumulate) + fused epilogues --
// EPI 0: QKV -> scatter to grouped q/k/v (+bias fp32, q*scale)
// EPI 1: proj -> outF (fp32) = acc + bias + resF (original x, fp32)
// EPI 2: fc1 chunk -> outB (bf16) = gelu_exact(acc + bias)
// EPI 4: fc2 chunk (not last) -> outF += acc
// EPI 5: fc2 last chunk -> outF = resF + acc + bias   (resF = xr, outF = d_out)
template<int EPI>
__global__ __launch_bounds__(256)
void gemm_epi(const bf16* __restrict__ A, const bf16* __restrict__ B,
              const float* __restrict__ bias, const float* __restrict__ resF,
              float* __restrict__ outF, bf16* __restrict__ outB,
              bf16* __restrict__ outQ, bf16* __restrict__ outK, bf16* __restrict__ outV,
              const int M, const int N, const int K, const int ldb)
{
  __shared__ float As[16][68];
  __shared__ float Bs[16][68];
  const int t = threadIdx.x;
  const int tx = t & 15, ty = t >> 4;
  const int m0 = blockIdx.x << 6, n0 = blockIdx.y << 6;
  const int ar = t >> 2, akq = (t & 3) << 2;      // A tile: 64 rows x 16 k
  const int bkr = t >> 4, bnq = (t & 15) << 2;    // B tile: 16 k x 64 n

  const bf16* aptr = A + (size_t)(m0 + ar) * K + akq;
  const bf16* bptr = B + (size_t)bkr * ldb + n0 + bnq;

  float acc[4][4];
#pragma unroll
  for (int i = 0; i < 4; ++i)
#pragma unroll
    for (int j = 0; j < 4; ++j) acc[i][j] = 0.f;

  for (int kt = 0; kt < K; kt += 16) {
    const ushort4 av = *reinterpret_cast<const ushort4*>(aptr); aptr += 16;
    const ushort4 bv = *reinterpret_cast<const ushort4*>(bptr); bptr += (size_t)16 * ldb;
    As[akq + 0][ar] = b2f(av.x);
    As[akq + 1][ar] = b2f(av.y);
    As[akq + 2][ar] = b2f(av.z);
    As[akq + 3][ar] = b2f(av.w);
    Bs[bkr][bnq + 0] = b2f(bv.x);
    Bs[bkr][bnq + 1] = b2f(bv.y);
    Bs[bkr][bnq + 2] = b2f(bv.z);
    Bs[bkr][bnq + 3] = b2f(bv.w);
    __syncthreads();
#pragma unroll
    for (int kk = 0; kk < 16; ++kk) {
      float a[4], b[4];
#pragma unroll
      for (int i = 0; i < 4; ++i) a[i] = As[kk][ty * 4 + i];
#pragma unroll
      for (int j = 0; j < 4; ++j) b[j] = Bs[kk][tx * 4 + j];
#pragma unroll
      for (int i = 0; i < 4; ++i)
#pragma unroll
        for (int j = 0; j < 4; ++j) acc[i][j] += a[i] * b[j];
    }
    __syncthreads();
  }

#pragma unroll
  for (int i = 0; i < 4; ++i) {
    const int m = m0 + ty * 4 + i;
    if (EPI == 0) {
      const int bb = m / 3136, l = m % 3136;
      const int hh = l / 56, ww = l % 56;
      const int win = bb * 64 + (hh / 7) * 8 + (ww / 7);
      const int p = (hh % 7) * 7 + (ww % 7);
#pragma unroll
      for (int j = 0; j < 4; ++j) {
        const int n = n0 + tx * 4 + j;
        const float val = acc[i][j] + bias[n];
        const int which = n >> 8, head = (n >> 5) & 7, d = n & 31;
        const size_t idx = ((size_t)(win * 8 + head) * 49 + p) * 32 + d;
        if (which == 0)      outQ[idx] = __float2bfloat16(val * QSCALE);
        else if (which == 1) outK[idx] = __float2bfloat16(val);
        else                 outV[idx] = __float2bfloat16(val);
      }
    } else if (EPI == 1) {
#pragma unroll
      for (int j = 0; j < 4; ++j) {
        const int n = n0 + tx * 4 + j;
        outF[(size_t)m * N + n] = acc[i][j] + bias[n] + resF[(size_t)m * N + n];
      }
    } else if (EPI == 2) {
#pragma unroll
      for (int j = 0; j < 4; ++j) {
        const int n = n0 + tx * 4 + j;
        const float z = acc[i][j] + bias[n];
        const float ge = 0.5f * z * (1.f + erff(z * 0.7071067811865476f));
        outB[(size_t)m * N + n] = __float2bfloat16(ge);
      }
    } else if (EPI == 4) {
#pragma unroll
      for (int j = 0; j < 4; ++j) {
        const int n = n0 + tx * 4 + j;
        outF[(size_t)m * N + n] += acc[i][j];
      }
    } else {
#pragma unroll
      for (int j = 0; j < 4; ++j) {
        const int n = n0 + tx * 4 + j;
        outF[(size_t)m * N + n] = resF[(size_t)m * N + n] + acc[i][j] + bias[n];
      }
    }
  }
}

// ---------------- per-(window,head) attention ----------------
__global__ __launch_bounds__(256)
void attn_kernel(const bf16* __restrict__ q, const bf16* __restrict__ k,
                 const bf16* __restrict__ v, const float* __restrict__ rel_bias,
                 bf16* __restrict__ out)
{
  __shared__ float qs[49 * 36], ks[49 * 36], vs[49 * 36];
  __shared__ float Ss[49 * 49];
  const int bid = blockIdx.x;            // win*8 + head
  const int win = bid >> 3, head = bid & 7;
  const int t = threadIdx.x;
  const size_t base = (size_t)bid * 1568;  // 49*32

  for (int idx = t; idx < 1568; idx += 256) {
    const int r = idx >> 5, cc = idx & 31;
    qs[r * 36 + cc] = __bfloat162float(q[base + idx]);
    ks[r * 36 + cc] = __bfloat162float(k[base + idx]);
    vs[r * 36 + cc] = __bfloat162float(v[base + idx]);
  }
  __syncthreads();

  if (t < 245) {                         // 49 rows x 5 threads/row
    const int i = t / 5, js = t % 5;
    float4 qr[8];
    const float4* qp = reinterpret_cast<const float4*>(qs + i * 36);
#pragma unroll
    for (int c = 0; c < 8; ++c) qr[c] = qp[c];
    for (int j = js; j < 49; j += 5) {
      const float4* kp = reinterpret_cast<const float4*>(ks + j * 36);
      float s = 0.f;
#pragma unroll
      for (int c = 0; c < 8; ++c) {
        const float4 kv = kp[c];
        s += qr[c].x * kv.x + qr[c].y * kv.y + qr[c].z * kv.z + qr[c].w * kv.w;
      }
      Ss[i * 49 + j] = s + rel_bias[head * 2401 + i * 49 + j];
    }
  }
  __syncthreads();

  if (t < 49) {
    float mx = -1e30f;
    for (int j = 0; j < 49; ++j) mx = fmaxf(mx, Ss[t * 49 + j]);
    float sum = 0.f;
    for (int j = 0; j < 49; ++j) { const float e = __expf(Ss[t * 49 + j] - mx); Ss[t * 49 + j] = e; sum += e; }
    const float inv = 1.f / sum;
    for (int j = 0; j < 49; ++j) Ss[t * 49 + j] *= inv;
  }
  __syncthreads();

  const int b = win >> 6, wh = (win >> 3) & 7, wwd = win & 7;
  for (int item = t; item < 392; item += 256) {   // 49 rows x 8 d-quads
    const int i = item >> 3, dq = item & 7;
    float4 o = make_float4(0.f, 0.f, 0.f, 0.f);
    for (int j = 0; j < 49; ++j) {
      const float s = Ss[i * 49 + j];
      const float4 vv = *reinterpret_cast<const float4*>(vs + j * 36 + dq * 4);
      o.x += s * vv.x; o.y += s * vv.y; o.z += s * vv.z; o.w += s * vv.w;
    }
    const int r = i / 7, cc = i % 7;
    const int tok = b * 3136 + (wh * 7 + r) * 56 + (wwd * 7 + cc);
    bf16* op = out + (size_t)tok * 256 + head * 32 + dq * 4;
    op[0] = __float2bfloat16(o.x);
    op[1] = __float2bfloat16(o.y);
    op[2] = __float2bfloat16(o.z);
    op[3] = __float2bfloat16(o.w);
  }
}

// ---------------- launch ----------------
// Workspace (~198 MB):
//   [0, 128KB)   rel_bias (fp32, 77KB)
//   [128KB, 2MB) bf16 weights: qkv_w(384KB) proj_w(128KB) fc1_w(512KB) fc2_w(512KB)
//   R1..R4: 4 regions of REG = NTOK*256*2 bytes each
//   R1: xn -> attn_out -> Hc        R2+R3: q,k -> xr (fp32)      R4: v -> yn
extern "C" void kernel_launch(void* const* d_in, const int* in_sizes, int n_in,
                              void* d_out, int out_size, void* d_ws, size_t ws_size,
                              hipStream_t stream)
{
  const float* x      = (const float*)d_in[0];
  const float* n1g    = (const float*)d_in[1];
  const float* n1b    = (const float*)d_in[2];
  const float* qkv_w  = (const float*)d_in[3];
  const float* qkv_b  = (const float*)d_in[4];
  const float* proj_w = (const float*)d_in[5];
  const float* proj_b = (const float*)d_in[6];
  const float* pp_w   = (const float*)d_in[7];
  const float* pp_b   = (const float*)d_in[8];
  const float* p1g    = (const float*)d_in[9];
  const float* p1lb   = (const float*)d_in[10];
  const float* p1w    = (const float*)d_in[11];
  const float* p1b    = (const float*)d_in[12];
  const float* p2g    = (const float*)d_in[13];
  const float* p2lb   = (const float*)d_in[14];
  const float* p2w    = (const float*)d_in[15];
  const float* p2b    = (const float*)d_in[16];
  const float* p3g    = (const float*)d_in[17];
  const float* p3lb   = (const float*)d_in[18];
  const float* p3w    = (const float*)d_in[19];
  const float* p3b    = (const float*)d_in[20];
  const float* n2g    = (const float*)d_in[21];
  const float* n2b    = (const float*)d_in[22];
  const float* fc1_w  = (const float*)d_in[23];
  const float* fc1_b  = (const float*)d_in[24];
  const float* fc2_w  = (const float*)d_in[25];
  const float* fc2_b  = (const float*)d_in[26];

  const size_t REG = (size_t)NTOK * 256 * 2;   // 51,380,224
  char* ws = (char*)d_ws;
  float* rel_bias = (float*)ws;
  bf16* wqkv = (bf16*)(ws + 131072);
  bf16* wproj = wqkv + 196608;
  bf16* wfc1 = wproj + 65536;
  bf16* wfc2 = wfc1 + 262144;
  char* R1 = ws + (2 << 20);
  char* R2 = R1 + REG;
  char* R3 = R2 + REG;
  char* R4 = R3 + REG;

  bf16*  xn   = (bf16*)R1;        // phase 1
  bf16*  qb   = (bf16*)R2;
  bf16*  kb   = (bf16*)R3;
  bf16*  vb   = (bf16*)R4;
  bf16*  aout = (bf16*)R1;        // phase 2 (xn dead)
  float* xr   = (float*)R2;       // phase 3 (q,k dead) — spans R2+R3
  bf16*  yn   = (bf16*)R4;        // phase 4 (v dead)
  bf16*  Hc   = (bf16*)R1;        // phase 5 (aout dead) — per-chunk hidden

  // one-off weight conversion fp32 -> bf16
  cvt_kernel<<<(196608 + 255) / 256, 256, 0, stream>>>(qkv_w, wqkv, 196608);
  cvt_kernel<<<(65536 + 255) / 256, 256, 0, stream>>>(proj_w, wproj, 65536);
  cvt_kernel<<<(262144 + 255) / 256, 256, 0, stream>>>(fc1_w, wfc1, 262144);
  cvt_kernel<<<(262144 + 255) / 256, 256, 0, stream>>>(fc2_w, wfc2, 262144);

  pos_kernel<<<1, 256, 0, stream>>>(pp_w, pp_b, p1g, p1lb, p1w, p1b,
                                    p2g, p2lb, p2w, p2b, p3g, p3lb, p3w, p3b, rel_bias);
  ln_kernel<<<NTOK, 256, 0, stream>>>(x, n1g, n1b, xn);
  gemm_epi<0><<<dim3(NTOK / 64, 12), 256, 0, stream>>>(xn, wqkv, qkv_b, nullptr,
      nullptr, nullptr, qb, kb, vb, NTOK, 768, 256, 768);
  attn_kernel<<<16384, 256, 0, stream>>>(qb, kb, vb, rel_bias, aout);
  gemm_epi<1><<<dim3(NTOK / 64, 4), 256, 0, stream>>>(aout, wproj, proj_b, x,
      xr, nullptr, nullptr, nullptr, nullptr, NTOK, 256, 256, 256);
  ln_kernel<<<NTOK, 256, 0, stream>>>(xr, n2g, n2b, yn);

  // MLP in 4 hidden-chunks of 256:
  //   Hc = gelu(yn @ fc1_w[:, c*256:(c+1)*256] + fc1_b[c])
  //   xr += Hc @ fc2_w[c*256:(c+1)*256, :]   (last chunk: d_out = xr + acc + fc2_b)
  for (int c = 0; c < 4; ++c) {
    gemm_epi<2><<<dim3(NTOK / 64, 4), 256, 0, stream>>>(yn, wfc1 + 256 * c, fc1_b + 256 * c,
        nullptr, nullptr, Hc, nullptr, nullptr, nullptr, NTOK, 256, 256, 1024);
    if (c < 3)
      gemm_epi<4><<<dim3(NTOK / 64, 4), 256, 0, stream>>>(Hc, wfc2 + (size_t)256 * c * 256,
          fc2_b, nullptr, xr, nullptr, nullptr, nullptr, nullptr, NTOK, 256, 256, 256);
    else
      gemm_epi<5><<<dim3(NTOK / 64, 4), 256, 0, stream>>>(Hc, wfc2 + (size_t)256 * c * 256,
          fc2_b, xr, (float*)d_out, nullptr, nullptr, nullptr, nullptr, NTOK, 256, 256, 256);
  }
}

// Round 4
// 1096.578 us; speedup vs baseline: 2.4206x; 2.4206x over previous
//
#include <hip/hip_runtime.h>
#include <hip/hip_bf16.h>
#include <math.h>

typedef __hip_bfloat16 bf16;
typedef unsigned short u16;
typedef unsigned int   u32;
typedef __bf16  bf16x8 __attribute__((ext_vector_type(8)));
typedef float   f32x4  __attribute__((ext_vector_type(4)));

#define NTOK 100352   // 32 * 56 * 56
#define QSCALE 0.17677669529663687f

// ---------------- fp32 -> bf16 transpose (weights, one-off) ----------------
// src[K][N] (row-major) -> dst[N][K] (row-major)
__global__ __launch_bounds__(256)
void cvt_t_kernel(const float* __restrict__ src, bf16* __restrict__ dst, int K, int N)
{
  const int i = blockIdx.x * 256 + threadIdx.x;
  if (i < K * N) {
    const int k = i / N, n = i % N;
    dst[(size_t)n * K + k] = __float2bfloat16(src[i]);
  }
}

// ---------------- pos-bias MLP + rel_bias table (1 block) ----------------
__device__ __forceinline__ void ln16_relu(float* cur, const float* g, const float* b) {
  float mu = 0.f;
#pragma unroll
  for (int j = 0; j < 16; ++j) mu += cur[j];
  mu *= (1.f / 16.f);
  float var = 0.f;
#pragma unroll
  for (int j = 0; j < 16; ++j) { float d = cur[j] - mu; var += d * d; }
  var *= (1.f / 16.f);
  const float r = rsqrtf(var + 1e-5f);
#pragma unroll
  for (int j = 0; j < 16; ++j) {
    float y = (cur[j] - mu) * r * g[j] + b[j];
    cur[j] = fmaxf(y, 0.f);
  }
}

__global__ __launch_bounds__(256)
void pos_kernel(const float* __restrict__ ppw, const float* __restrict__ ppb,
                const float* __restrict__ g1, const float* __restrict__ lb1,
                const float* __restrict__ w1, const float* __restrict__ b1,
                const float* __restrict__ g2, const float* __restrict__ lb2,
                const float* __restrict__ w2, const float* __restrict__ b2,
                const float* __restrict__ g3, const float* __restrict__ lb3,
                const float* __restrict__ w3, const float* __restrict__ b3,
                float* __restrict__ rel_bias)
{
  __shared__ float pos_s[169 * 8];
  const int t = threadIdx.x;
  if (t < 169) {
    float cur[16], nxt[16];
    const float bh = (float)(t / 13 - 6), bw = (float)(t % 13 - 6);
#pragma unroll
    for (int j = 0; j < 16; ++j)
      cur[j] = bh * ppw[j] + bw * ppw[16 + j] + ppb[j];
    ln16_relu(cur, g1, lb1);
    for (int j = 0; j < 16; ++j) nxt[j] = b1[j];
    for (int k = 0; k < 16; ++k) { float a = cur[k]; for (int j = 0; j < 16; ++j) nxt[j] += a * w1[k * 16 + j]; }
    for (int j = 0; j < 16; ++j) cur[j] = nxt[j];
    ln16_relu(cur, g2, lb2);
    for (int j = 0; j < 16; ++j) nxt[j] = b2[j];
    for (int k = 0; k < 16; ++k) { float a = cur[k]; for (int j = 0; j < 16; ++j) nxt[j] += a * w2[k * 16 + j]; }
    for (int j = 0; j < 16; ++j) cur[j] = nxt[j];
    ln16_relu(cur, g3, lb3);
    for (int h = 0; h < 8; ++h) {
      float s = b3[h];
      for (int k = 0; k < 16; ++k) s += cur[k] * w3[k * 8 + h];
      pos_s[t * 8 + h] = s;
    }
  }
  __syncthreads();
  for (int e = t; e < 8 * 2401; e += 256) {
    const int h = e / 2401, ij = e % 2401, i = ij / 49, j = ij % 49;
    const int dh = i / 7 - j / 7 + 6, dw = i % 7 - j % 7 + 6;
    rel_bias[e] = pos_s[(dh * 13 + dw) * 8 + h];
  }
}

// ---------------- LayerNorm over C=256 (fp32 in, bf16 out) ----------------
__global__ __launch_bounds__(256)
void ln_kernel(const float* __restrict__ xin,
               const float* __restrict__ g, const float* __restrict__ b,
               bf16* __restrict__ out)
{
  const int tok = blockIdx.x, c = threadIdx.x;
  const float xv = xin[(size_t)tok * 256 + c];
  __shared__ float red[256];
  red[c] = xv; __syncthreads();
#pragma unroll
  for (int s = 128; s > 0; s >>= 1) { if (c < s) red[c] += red[c + s]; __syncthreads(); }
  const float mu = red[0] * (1.f / 256.f);
  __syncthreads();
  const float d = xv - mu;
  red[c] = d * d; __syncthreads();
#pragma unroll
  for (int s = 128; s > 0; s >>= 1) { if (c < s) red[c] += red[c + s]; __syncthreads(); }
  const float rstd = rsqrtf(red[0] * (1.f / 256.f) + 1e-5f);
  const float y = d * rstd * g[c] + b[c];
  out[(size_t)tok * 256 + c] = __float2bfloat16(y);
}

// ---------------- MFMA GEMM: C[M,N] = A[M,K] @ BT[N,K]^T + epilogue ------
// 128x128 tile, BK=32, 4 waves, each wave 64x64 via 4x4 of 16x16x32 MFMA.
// A, BT bf16 row-major (lda=K, ldbt=K). M,N multiples of 128; K of 32.
// EPI 0: QKV -> scatter to grouped q/k/v (+bias fp32, q*scale)
// EPI 1: proj -> outF (fp32) = acc + bias + resF
// EPI 2: fc1  -> outB (bf16) = gelu_exact(acc + bias)
// EPI 5: fc2  -> outF (fp32) = resF + acc + bias
template<int EPI>
__global__ __launch_bounds__(256, 2)
void gemm_mfma(const bf16* __restrict__ A, const bf16* __restrict__ BT,
               const float* __restrict__ bias, const float* __restrict__ resF,
               float* __restrict__ outF, bf16* __restrict__ outB,
               bf16* __restrict__ outQ, bf16* __restrict__ outK, bf16* __restrict__ outV,
               const int M, const int N, const int K)
{
  __shared__ __align__(16) u16 Alds[128 * 32];
  __shared__ __align__(16) u16 Blds[128 * 32];
  const int t = threadIdx.x;
  const int m0 = blockIdx.x << 7, n0 = blockIdx.y << 7;
  const int wave = t >> 6, lane = t & 63;
  const int quad = lane >> 4, l15 = lane & 15;
  const int mw = (wave & 1) << 6, nw = (wave >> 1) << 6;

  // staging: thread t loads 16B (8 bf16) -> row t/4, col-block (t&3)*8
  const int sr = t >> 2, sc = (t & 3) << 3;
  const bf16* ag0 = A  + (size_t)(m0 + sr) * K + sc;
  const bf16* ag1 = ag0 + (size_t)64 * K;
  const bf16* bg0 = BT + (size_t)(n0 + sr) * K + sc;
  const bf16* bg1 = bg0 + (size_t)64 * K;
  char* alds0 = (char*)Alds + t * 16;
  char* alds1 = (char*)Alds + 4096 + t * 16;
  char* blds0 = (char*)Blds + t * 16;
  char* blds1 = (char*)Blds + 4096 + t * 16;

  f32x4 acc[4][4];
#pragma unroll
  for (int mi = 0; mi < 4; ++mi)
#pragma unroll
    for (int ni = 0; ni < 4; ++ni) acc[mi][ni] = (f32x4){0.f, 0.f, 0.f, 0.f};

  for (int kt = 0; kt < K; kt += 32) {
    __builtin_amdgcn_global_load_lds((const __attribute__((address_space(1))) void*)(ag0 + kt),
        (__attribute__((address_space(3))) void*)alds0, 16, 0, 0);
    __builtin_amdgcn_global_load_lds((const __attribute__((address_space(1))) void*)(ag1 + kt),
        (__attribute__((address_space(3))) void*)alds1, 16, 0, 0);
    __builtin_amdgcn_global_load_lds((const __attribute__((address_space(1))) void*)(bg0 + kt),
        (__attribute__((address_space(3))) void*)blds0, 16, 0, 0);
    __builtin_amdgcn_global_load_lds((const __attribute__((address_space(1))) void*)(bg1 + kt),
        (__attribute__((address_space(3))) void*)blds1, 16, 0, 0);
    __syncthreads();

    bf16x8 af[4], bfr[4];
#pragma unroll
    for (int mi = 0; mi < 4; ++mi)
      af[mi] = *(const bf16x8*)(Alds + (mw + mi * 16 + l15) * 32 + quad * 8);
#pragma unroll
    for (int ni = 0; ni < 4; ++ni)
      bfr[ni] = *(const bf16x8*)(Blds + (nw + ni * 16 + l15) * 32 + quad * 8);
#pragma unroll
    for (int mi = 0; mi < 4; ++mi)
#pragma unroll
      for (int ni = 0; ni < 4; ++ni)
        acc[mi][ni] = __builtin_amdgcn_mfma_f32_16x16x32_bf16(af[mi], bfr[ni], acc[mi][ni], 0, 0, 0);
    __syncthreads();
  }

  // epilogue: lane holds D[row=quad*4+r][col=l15] per 16x16 subtile
#pragma unroll
  for (int mi = 0; mi < 4; ++mi) {
#pragma unroll
    for (int r = 0; r < 4; ++r) {
      const int m = m0 + mw + mi * 16 + quad * 4 + r;
      if (EPI == 0) {
        const int bb = m / 3136, l = m % 3136;
        const int hh = l / 56, ww = l % 56;
        const int win = bb * 64 + (hh / 7) * 8 + (ww / 7);
        const int p = (hh % 7) * 7 + (ww % 7);
        const size_t tokbase = ((size_t)win * 8) * 1568 + (size_t)p * 32; // + head*1568 + d
#pragma unroll
        for (int ni = 0; ni < 4; ++ni) {
          const int n = n0 + nw + ni * 16 + l15;
          const float val = acc[mi][ni][r] + bias[n];
          const int which = n >> 8, head = (n >> 5) & 7, d = n & 31;
          const size_t idx = tokbase + (size_t)head * 1568 + d;
          if (which == 0)      outQ[idx] = __float2bfloat16(val * QSCALE);
          else if (which == 1) outK[idx] = __float2bfloat16(val);
          else                 outV[idx] = __float2bfloat16(val);
        }
      } else if (EPI == 1) {
#pragma unroll
        for (int ni = 0; ni < 4; ++ni) {
          const int n = n0 + nw + ni * 16 + l15;
          outF[(size_t)m * N + n] = acc[mi][ni][r] + bias[n] + resF[(size_t)m * N + n];
        }
      } else if (EPI == 2) {
#pragma unroll
        for (int ni = 0; ni < 4; ++ni) {
          const int n = n0 + nw + ni * 16 + l15;
          const float z = acc[mi][ni][r] + bias[n];
          const float ge = 0.5f * z * (1.f + erff(z * 0.7071067811865476f));
          outB[(size_t)m * N + n] = __float2bfloat16(ge);
        }
      } else {
#pragma unroll
        for (int ni = 0; ni < 4; ++ni) {
          const int n = n0 + nw + ni * 16 + l15;
          outF[(size_t)m * N + n] = resF[(size_t)m * N + n] + acc[mi][ni][r] + bias[n];
        }
      }
    }
  }
}

// ---------------- per-(window,head) attention ----------------
__global__ __launch_bounds__(256)
void attn_kernel(const bf16* __restrict__ q, const bf16* __restrict__ k,
                 const bf16* __restrict__ v, const float* __restrict__ rel_bias,
                 bf16* __restrict__ out)
{
  __shared__ float qs[49 * 36], ks[49 * 36], vs[49 * 36];
  __shared__ float Ss[49 * 49];
  const int bid = blockIdx.x;            // win*8 + head
  const int win = bid >> 3, head = bid & 7;
  const int t = threadIdx.x;
  const size_t base = (size_t)bid * 1568;  // 49*32

  for (int idx = t; idx < 1568; idx += 256) {
    const int r = idx >> 5, cc = idx & 31;
    qs[r * 36 + cc] = __bfloat162float(q[base + idx]);
    ks[r * 36 + cc] = __bfloat162float(k[base + idx]);
    vs[r * 36 + cc] = __bfloat162float(v[base + idx]);
  }
  __syncthreads();

  if (t < 245) {                         // 49 rows x 5 threads/row
    const int i = t / 5, js = t % 5;
    float4 qr[8];
    const float4* qp = reinterpret_cast<const float4*>(qs + i * 36);
#pragma unroll
    for (int c = 0; c < 8; ++c) qr[c] = qp[c];
    for (int j = js; j < 49; j += 5) {
      const float4* kp = reinterpret_cast<const float4*>(ks + j * 36);
      float s = 0.f;
#pragma unroll
      for (int c = 0; c < 8; ++c) {
        const float4 kv = kp[c];
        s += qr[c].x * kv.x + qr[c].y * kv.y + qr[c].z * kv.z + qr[c].w * kv.w;
      }
      Ss[i * 49 + j] = s + rel_bias[head * 2401 + i * 49 + j];
    }
  }
  __syncthreads();

  if (t < 49) {
    float mx = -1e30f;
    for (int j = 0; j < 49; ++j) mx = fmaxf(mx, Ss[t * 49 + j]);
    float sum = 0.f;
    for (int j = 0; j < 49; ++j) { const float e = __expf(Ss[t * 49 + j] - mx); Ss[t * 49 + j] = e; sum += e; }
    const float inv = 1.f / sum;
    for (int j = 0; j < 49; ++j) Ss[t * 49 + j] *= inv;
  }
  __syncthreads();

  const int b = win >> 6, wh = (win >> 3) & 7, wwd = win & 7;
  for (int item = t; item < 392; item += 256) {   // 49 rows x 8 d-quads
    const int i = item >> 3, dq = item & 7;
    float4 o = make_float4(0.f, 0.f, 0.f, 0.f);
    for (int j = 0; j < 49; ++j) {
      const float s = Ss[i * 49 + j];
      const float4 vv = *reinterpret_cast<const float4*>(vs + j * 36 + dq * 4);
      o.x += s * vv.x; o.y += s * vv.y; o.z += s * vv.z; o.w += s * vv.w;
    }
    const int r = i / 7, cc = i % 7;
    const int tok = b * 3136 + (wh * 7 + r) * 56 + (wwd * 7 + cc);
    bf16* op = out + (size_t)tok * 256 + head * 32 + dq * 4;
    op[0] = __float2bfloat16(o.x);
    op[1] = __float2bfloat16(o.y);
    op[2] = __float2bfloat16(o.z);
    op[3] = __float2bfloat16(o.w);
  }
}

// ---------------- launch ----------------
// Workspace (~198 MB):
//   [0, 128KB)   rel_bias (fp32, 77KB)
//   [128KB, 2MB) bf16 transposed weights: qkvT[768][256] projT[256][256]
//                fc1T[1024][256] fc2T[256][1024]
//   R1..R4: 4 regions of REG = NTOK*256*2 bytes each
//   R1: xn -> attn_out -> Hc (per-M-chunk hidden, 25088x1024 bf16)
//   R2+R3: q,k -> xr (fp32)      R4: v -> yn
extern "C" void kernel_launch(void* const* d_in, const int* in_sizes, int n_in,
                              void* d_out, int out_size, void* d_ws, size_t ws_size,
                              hipStream_t stream)
{
  const float* x      = (const float*)d_in[0];
  const float* n1g    = (const float*)d_in[1];
  const float* n1b    = (const float*)d_in[2];
  const float* qkv_w  = (const float*)d_in[3];
  const float* qkv_b  = (const float*)d_in[4];
  const float* proj_w = (const float*)d_in[5];
  const float* proj_b = (const float*)d_in[6];
  const float* pp_w   = (const float*)d_in[7];
  const float* pp_b   = (const float*)d_in[8];
  const float* p1g    = (const float*)d_in[9];
  const float* p1lb   = (const float*)d_in[10];
  const float* p1w    = (const float*)d_in[11];
  const float* p1b    = (const float*)d_in[12];
  const float* p2g    = (const float*)d_in[13];
  const float* p2lb   = (const float*)d_in[14];
  const float* p2w    = (const float*)d_in[15];
  const float* p2b    = (const float*)d_in[16];
  const float* p3g    = (const float*)d_in[17];
  const float* p3lb   = (const float*)d_in[18];
  const float* p3w    = (const float*)d_in[19];
  const float* p3b    = (const float*)d_in[20];
  const float* n2g    = (const float*)d_in[21];
  const float* n2b    = (const float*)d_in[22];
  const float* fc1_w  = (const float*)d_in[23];
  const float* fc1_b  = (const float*)d_in[24];
  const float* fc2_w  = (const float*)d_in[25];
  const float* fc2_b  = (const float*)d_in[26];

  const size_t REG = (size_t)NTOK * 256 * 2;   // 51,380,224
  char* ws = (char*)d_ws;
  float* rel_bias = (float*)ws;
  bf16* wqkvT = (bf16*)(ws + 131072);
  bf16* wprojT = wqkvT + 196608;
  bf16* wfc1T = wprojT + 65536;
  bf16* wfc2T = wfc1T + 262144;
  char* R1 = ws + (2 << 20);
  char* R2 = R1 + REG;
  char* R3 = R2 + REG;
  char* R4 = R3 + REG;

  bf16*  xn   = (bf16*)R1;        // phase 1
  bf16*  qb   = (bf16*)R2;
  bf16*  kb   = (bf16*)R3;
  bf16*  vb   = (bf16*)R4;
  bf16*  aout = (bf16*)R1;        // phase 2 (xn dead)
  float* xr   = (float*)R2;       // phase 3 (q,k dead) — spans R2+R3
  bf16*  yn   = (bf16*)R4;        // phase 4 (v dead)
  bf16*  Hc   = (bf16*)R1;        // phase 5 (aout dead) — per-M-chunk hidden

  // one-off weight conversion + transpose fp32 [K][N] -> bf16 [N][K]
  cvt_t_kernel<<<(196608 + 255) / 256, 256, 0, stream>>>(qkv_w, wqkvT, 256, 768);
  cvt_t_kernel<<<(65536 + 255) / 256, 256, 0, stream>>>(proj_w, wprojT, 256, 256);
  cvt_t_kernel<<<(262144 + 255) / 256, 256, 0, stream>>>(fc1_w, wfc1T, 256, 1024);
  cvt_t_kernel<<<(262144 + 255) / 256, 256, 0, stream>>>(fc2_w, wfc2T, 1024, 256);

  pos_kernel<<<1, 256, 0, stream>>>(pp_w, pp_b, p1g, p1lb, p1w, p1b,
                                    p2g, p2lb, p2w, p2b, p3g, p3lb, p3w, p3b, rel_bias);
  ln_kernel<<<NTOK, 256, 0, stream>>>(x, n1g, n1b, xn);
  gemm_mfma<0><<<dim3(NTOK / 128, 6), 256, 0, stream>>>(xn, wqkvT, qkv_b, nullptr,
      nullptr, nullptr, qb, kb, vb, NTOK, 768, 256);
  attn_kernel<<<16384, 256, 0, stream>>>(qb, kb, vb, rel_bias, aout);
  gemm_mfma<1><<<dim3(NTOK / 128, 2), 256, 0, stream>>>(aout, wprojT, proj_b, x,
      xr, nullptr, nullptr, nullptr, nullptr, NTOK, 256, 256);
  ln_kernel<<<NTOK, 256, 0, stream>>>(xr, n2g, n2b, yn);

  // MLP in 4 M-chunks of 25088 tokens (hidden chunk fits one region):
  //   Hc = gelu(yn_chunk @ fc1)   then   d_out_chunk = xr_chunk + Hc @ fc2 + b
  const int MC = 25088;
  for (int c = 0; c < 4; ++c) {
    const size_t mb = (size_t)c * MC;
    gemm_mfma<2><<<dim3(MC / 128, 8), 256, 0, stream>>>(yn + mb * 256, wfc1T,
        fc1_b, nullptr, nullptr, Hc, nullptr, nullptr, nullptr, MC, 1024, 256);
    gemm_mfma<5><<<dim3(MC / 128, 2), 256, 0, stream>>>(Hc, wfc2T,
        fc2_b, xr + mb * 256, (float*)d_out + mb * 256, nullptr, nullptr, nullptr, nullptr,
        MC, 256, 1024);
  }
}

// Round 5
// 782.748 us; speedup vs baseline: 3.3910x; 1.4009x over previous
//
#include <hip/hip_runtime.h>
#include <hip/hip_bf16.h>
#include <math.h>

typedef __hip_bfloat16 bf16;
typedef unsigned short u16;
typedef unsigned int   u32;
typedef __bf16  bf16x8 __attribute__((ext_vector_type(8)));
typedef float   f32x4  __attribute__((ext_vector_type(4)));

#define NTOK 100352   // 32 * 56 * 56
#define QSCALE 0.17677669529663687f

// ---------------- fp32 -> bf16 transpose (weights, one-off) ----------------
__global__ __launch_bounds__(256)
void cvt_t_kernel(const float* __restrict__ src, bf16* __restrict__ dst, int K, int N)
{
  const int i = blockIdx.x * 256 + threadIdx.x;
  if (i < K * N) {
    const int k = i / N, n = i % N;
    dst[(size_t)n * K + k] = __float2bfloat16(src[i]);
  }
}

// ---------------- pos-bias MLP + rel_bias table (1 block) ----------------
__device__ __forceinline__ void ln16_relu(float* cur, const float* g, const float* b) {
  float mu = 0.f;
#pragma unroll
  for (int j = 0; j < 16; ++j) mu += cur[j];
  mu *= (1.f / 16.f);
  float var = 0.f;
#pragma unroll
  for (int j = 0; j < 16; ++j) { float d = cur[j] - mu; var += d * d; }
  var *= (1.f / 16.f);
  const float r = rsqrtf(var + 1e-5f);
#pragma unroll
  for (int j = 0; j < 16; ++j) {
    float y = (cur[j] - mu) * r * g[j] + b[j];
    cur[j] = fmaxf(y, 0.f);
  }
}

__global__ __launch_bounds__(256)
void pos_kernel(const float* __restrict__ ppw, const float* __restrict__ ppb,
                const float* __restrict__ g1, const float* __restrict__ lb1,
                const float* __restrict__ w1, const float* __restrict__ b1,
                const float* __restrict__ g2, const float* __restrict__ lb2,
                const float* __restrict__ w2, const float* __restrict__ b2,
                const float* __restrict__ g3, const float* __restrict__ lb3,
                const float* __restrict__ w3, const float* __restrict__ b3,
                float* __restrict__ rel_bias)
{
  __shared__ float pos_s[169 * 8];
  const int t = threadIdx.x;
  if (t < 169) {
    float cur[16], nxt[16];
    const float bh = (float)(t / 13 - 6), bw = (float)(t % 13 - 6);
#pragma unroll
    for (int j = 0; j < 16; ++j)
      cur[j] = bh * ppw[j] + bw * ppw[16 + j] + ppb[j];
    ln16_relu(cur, g1, lb1);
    for (int j = 0; j < 16; ++j) nxt[j] = b1[j];
    for (int k = 0; k < 16; ++k) { float a = cur[k]; for (int j = 0; j < 16; ++j) nxt[j] += a * w1[k * 16 + j]; }
    for (int j = 0; j < 16; ++j) cur[j] = nxt[j];
    ln16_relu(cur, g2, lb2);
    for (int j = 0; j < 16; ++j) nxt[j] = b2[j];
    for (int k = 0; k < 16; ++k) { float a = cur[k]; for (int j = 0; j < 16; ++j) nxt[j] += a * w2[k * 16 + j]; }
    for (int j = 0; j < 16; ++j) cur[j] = nxt[j];
    ln16_relu(cur, g3, lb3);
    for (int h = 0; h < 8; ++h) {
      float s = b3[h];
      for (int k = 0; k < 16; ++k) s += cur[k] * w3[k * 8 + h];
      pos_s[t * 8 + h] = s;
    }
  }
  __syncthreads();
  for (int e = t; e < 8 * 2401; e += 256) {
    const int h = e / 2401, ij = e % 2401, i = ij / 49, j = ij % 49;
    const int dh = i / 7 - j / 7 + 6, dw = i % 7 - j % 7 + 6;
    rel_bias[e] = pos_s[(dh * 13 + dw) * 8 + h];
  }
}

// ---------------- LayerNorm over C=256: one wave per token ----------------
__global__ __launch_bounds__(256)
void ln_wave(const float* __restrict__ xin,
             const float* __restrict__ g, const float* __restrict__ b,
             bf16* __restrict__ out)
{
  const int tok = blockIdx.x * 4 + (threadIdx.x >> 6);
  const int lane = threadIdx.x & 63;
  const float4 xv = *reinterpret_cast<const float4*>(xin + (size_t)tok * 256 + lane * 4);
  float s = xv.x + xv.y + xv.z + xv.w;
#pragma unroll
  for (int off = 1; off < 64; off <<= 1) s += __shfl_xor(s, off, 64);
  const float mu = s * (1.f / 256.f);
  const float4 dx = make_float4(xv.x - mu, xv.y - mu, xv.z - mu, xv.w - mu);
  float v = dx.x * dx.x + dx.y * dx.y + dx.z * dx.z + dx.w * dx.w;
#pragma unroll
  for (int off = 1; off < 64; off <<= 1) v += __shfl_xor(v, off, 64);
  const float rstd = rsqrtf(v * (1.f / 256.f) + 1e-5f);
  const float4 gv = *reinterpret_cast<const float4*>(g + lane * 4);
  const float4 bv = *reinterpret_cast<const float4*>(b + lane * 4);
  bf16 o0 = __float2bfloat16(dx.x * rstd * gv.x + bv.x);
  bf16 o1 = __float2bfloat16(dx.y * rstd * gv.y + bv.y);
  bf16 o2 = __float2bfloat16(dx.z * rstd * gv.z + bv.z);
  bf16 o3 = __float2bfloat16(dx.w * rstd * gv.w + bv.w);
  ushort4 st = make_ushort4(*(u16*)&o0, *(u16*)&o1, *(u16*)&o2, *(u16*)&o3);
  *reinterpret_cast<ushort4*>(out + (size_t)tok * 256 + lane * 4) = st;
}

// ---------------- MFMA GEMM: C[M,N] = A[M,K] @ BT[N,K]^T + epilogue ------
template<int EPI>
__global__ __launch_bounds__(256, 2)
void gemm_mfma(const bf16* __restrict__ A, const bf16* __restrict__ BT,
               const float* __restrict__ bias, const float* __restrict__ resF,
               float* __restrict__ outF, bf16* __restrict__ outB,
               bf16* __restrict__ outQ, bf16* __restrict__ outK, bf16* __restrict__ outV,
               const int M, const int N, const int K)
{
  __shared__ __align__(16) u16 Alds[128 * 32];
  __shared__ __align__(16) u16 Blds[128 * 32];
  const int t = threadIdx.x;
  const int m0 = blockIdx.x << 7, n0 = blockIdx.y << 7;
  const int wave = t >> 6, lane = t & 63;
  const int quad = lane >> 4, l15 = lane & 15;
  const int mw = (wave & 1) << 6, nw = (wave >> 1) << 6;

  const int sr = t >> 2, sc = (t & 3) << 3;
  const bf16* ag0 = A  + (size_t)(m0 + sr) * K + sc;
  const bf16* ag1 = ag0 + (size_t)64 * K;
  const bf16* bg0 = BT + (size_t)(n0 + sr) * K + sc;
  const bf16* bg1 = bg0 + (size_t)64 * K;
  char* alds0 = (char*)Alds + t * 16;
  char* alds1 = (char*)Alds + 4096 + t * 16;
  char* blds0 = (char*)Blds + t * 16;
  char* blds1 = (char*)Blds + 4096 + t * 16;

  f32x4 acc[4][4];
#pragma unroll
  for (int mi = 0; mi < 4; ++mi)
#pragma unroll
    for (int ni = 0; ni < 4; ++ni) acc[mi][ni] = (f32x4){0.f, 0.f, 0.f, 0.f};

  for (int kt = 0; kt < K; kt += 32) {
    __builtin_amdgcn_global_load_lds((const __attribute__((address_space(1))) void*)(ag0 + kt),
        (__attribute__((address_space(3))) void*)alds0, 16, 0, 0);
    __builtin_amdgcn_global_load_lds((const __attribute__((address_space(1))) void*)(ag1 + kt),
        (__attribute__((address_space(3))) void*)alds1, 16, 0, 0);
    __builtin_amdgcn_global_load_lds((const __attribute__((address_space(1))) void*)(bg0 + kt),
        (__attribute__((address_space(3))) void*)blds0, 16, 0, 0);
    __builtin_amdgcn_global_load_lds((const __attribute__((address_space(1))) void*)(bg1 + kt),
        (__attribute__((address_space(3))) void*)blds1, 16, 0, 0);
    __syncthreads();

    bf16x8 af[4], bfr[4];
#pragma unroll
    for (int mi = 0; mi < 4; ++mi)
      af[mi] = *(const bf16x8*)(Alds + (mw + mi * 16 + l15) * 32 + quad * 8);
#pragma unroll
    for (int ni = 0; ni < 4; ++ni)
      bfr[ni] = *(const bf16x8*)(Blds + (nw + ni * 16 + l15) * 32 + quad * 8);
#pragma unroll
    for (int mi = 0; mi < 4; ++mi)
#pragma unroll
      for (int ni = 0; ni < 4; ++ni)
        acc[mi][ni] = __builtin_amdgcn_mfma_f32_16x16x32_bf16(af[mi], bfr[ni], acc[mi][ni], 0, 0, 0);
    __syncthreads();
  }

#pragma unroll
  for (int mi = 0; mi < 4; ++mi) {
#pragma unroll
    for (int r = 0; r < 4; ++r) {
      const int m = m0 + mw + mi * 16 + quad * 4 + r;
      if (EPI == 0) {
        const int bb = m / 3136, l = m % 3136;
        const int hh = l / 56, ww = l % 56;
        const int win = bb * 64 + (hh / 7) * 8 + (ww / 7);
        const int p = (hh % 7) * 7 + (ww % 7);
        const size_t tokbase = ((size_t)win * 8) * 1568 + (size_t)p * 32;
#pragma unroll
        for (int ni = 0; ni < 4; ++ni) {
          const int n = n0 + nw + ni * 16 + l15;
          const float val = acc[mi][ni][r] + bias[n];
          const int which = n >> 8, head = (n >> 5) & 7, d = n & 31;
          const size_t idx = tokbase + (size_t)head * 1568 + d;
          if (which == 0)      outQ[idx] = __float2bfloat16(val * QSCALE);
          else if (which == 1) outK[idx] = __float2bfloat16(val);
          else                 outV[idx] = __float2bfloat16(val);
        }
      } else if (EPI == 1) {
#pragma unroll
        for (int ni = 0; ni < 4; ++ni) {
          const int n = n0 + nw + ni * 16 + l15;
          outF[(size_t)m * N + n] = acc[mi][ni][r] + bias[n] + resF[(size_t)m * N + n];
        }
      } else if (EPI == 2) {
#pragma unroll
        for (int ni = 0; ni < 4; ++ni) {
          const int n = n0 + nw + ni * 16 + l15;
          const float z = acc[mi][ni][r] + bias[n];
          const float ge = 0.5f * z * (1.f + erff(z * 0.7071067811865476f));
          outB[(size_t)m * N + n] = __float2bfloat16(ge);
        }
      } else {
#pragma unroll
        for (int ni = 0; ni < 4; ++ni) {
          const int n = n0 + nw + ni * 16 + l15;
          outF[(size_t)m * N + n] = resF[(size_t)m * N + n] + acc[mi][ni][r] + bias[n];
        }
      }
    }
  }
}

// ---------------- MFMA attention: one wave per (window, head) ----------------
// LDS per block (13,824 B):
//   [0,4096)      Q [64][32] bf16   (rows 49..63 garbage, masked)
//   [4096,8192)   K [64][32] bf16   (rows 49..63 garbage -> S cols masked)
//   [0,9216)      P [64][72] bf16   (overlays Q,K after QK^T consumed)
//   [9216,13824)  VT [32][72] bf16  (V transposed, j>=49 zeroed)
__global__ __launch_bounds__(64)
void attn_mfma(const bf16* __restrict__ q, const bf16* __restrict__ k,
               const bf16* __restrict__ v, const float* __restrict__ rel_bias,
               bf16* __restrict__ out)
{
  __shared__ __align__(16) char lds[13824];
  u16* Qs = (u16*)lds;
  u16* Ks = (u16*)(lds + 4096);
  u16* Ps = (u16*)lds;
  u16* VT = (u16*)(lds + 9216);

  const int bid = blockIdx.x;           // win*8 + head
  const int win = bid >> 3, head = bid & 7;
  const int lane = threadIdx.x;
  const int quad = lane >> 4, l15 = lane & 15;
  const size_t base = (size_t)bid * 1568;

  // stage Q, K via global-to-LDS DMA (4 x 1024B each)
#pragma unroll
  for (int i = 0; i < 4; ++i) {
    __builtin_amdgcn_global_load_lds(
        (const __attribute__((address_space(1))) void*)(q + base + i * 512 + lane * 8),
        (__attribute__((address_space(3))) void*)((char*)Qs + i * 1024 + lane * 16), 16, 0, 0);
    __builtin_amdgcn_global_load_lds(
        (const __attribute__((address_space(1))) void*)(k + base + i * 512 + lane * 8),
        (__attribute__((address_space(3))) void*)((char*)Ks + i * 1024 + lane * 16), 16, 0, 0);
  }
  // stage V transposed: VT[d][j], pad j in [49,64) zeroed
  for (int idx = lane; idx < 1568; idx += 64) {
    const int j = idx >> 5, d = idx & 31;
    VT[d * 72 + j] = *(const u16*)(v + base + idx);
  }
  for (int idx = lane; idx < 480; idx += 64) {
    const int d = idx / 15, j = 49 + idx % 15;
    VT[d * 72 + j] = 0;
  }
  __builtin_amdgcn_s_waitcnt(0);
  __syncthreads();

  // QK^T: S[64][64] in 4x4 MFMA tiles
  bf16x8 qf[4], kf[4];
#pragma unroll
  for (int mi = 0; mi < 4; ++mi)
    qf[mi] = *(const bf16x8*)(Qs + (mi * 16 + l15) * 32 + quad * 8);
#pragma unroll
  for (int ni = 0; ni < 4; ++ni)
    kf[ni] = *(const bf16x8*)(Ks + (ni * 16 + l15) * 32 + quad * 8);
  f32x4 S[4][4];
#pragma unroll
  for (int mi = 0; mi < 4; ++mi)
#pragma unroll
    for (int ni = 0; ni < 4; ++ni)
      S[mi][ni] = __builtin_amdgcn_mfma_f32_16x16x32_bf16(qf[mi], kf[ni],
                                                          (f32x4){0.f, 0.f, 0.f, 0.f}, 0, 0, 0);

  // bias + mask, row softmax (rows = quad*4+r per tile; cols = l15 across 16 lanes)
  const float* rb = rel_bias + head * 2401;
  const int n_col = l15;                 // col within tile
#pragma unroll
  for (int mi = 0; mi < 4; ++mi) {
#pragma unroll
    for (int r = 0; r < 4; ++r) {
      const int m = mi * 16 + quad * 4 + r;
      const int mc = m < 49 ? m : 48;
      float sv[4];
#pragma unroll
      for (int ni = 0; ni < 4; ++ni) {
        const int n = ni * 16 + n_col;
        sv[ni] = (n < 49) ? (S[mi][ni][r] + rb[mc * 49 + n]) : -3e38f;
      }
      float mx = fmaxf(fmaxf(sv[0], sv[1]), fmaxf(sv[2], sv[3]));
#pragma unroll
      for (int off = 1; off < 16; off <<= 1) mx = fmaxf(mx, __shfl_xor(mx, off, 64));
      float sum = 0.f;
#pragma unroll
      for (int ni = 0; ni < 4; ++ni) { sv[ni] = __expf(sv[ni] - mx); sum += sv[ni]; }
#pragma unroll
      for (int off = 1; off < 16; off <<= 1) sum += __shfl_xor(sum, off, 64);
      const float inv = 1.f / sum;
#pragma unroll
      for (int ni = 0; ni < 4; ++ni) S[mi][ni][r] = sv[ni] * inv;
    }
  }
  __syncthreads();   // Q/K frag reads complete; safe to overlay P

  // write P to LDS in A-operand layout [m][j], ld=72
#pragma unroll
  for (int mi = 0; mi < 4; ++mi)
#pragma unroll
    for (int r = 0; r < 4; ++r) {
      const int m = mi * 16 + quad * 4 + r;
#pragma unroll
      for (int ni = 0; ni < 4; ++ni) {
        const bf16 pb = __float2bfloat16(S[mi][ni][r]);
        Ps[m * 72 + ni * 16 + l15] = *(const u16*)&pb;
      }
    }
  __syncthreads();

  // O = P @ V : A=P [64][64], B=VT [32][64] -> O [64][32]
  f32x4 O[4][2];
#pragma unroll
  for (int mi = 0; mi < 4; ++mi)
#pragma unroll
    for (int ni = 0; ni < 2; ++ni) O[mi][ni] = (f32x4){0.f, 0.f, 0.f, 0.f};
#pragma unroll
  for (int kt = 0; kt < 2; ++kt) {
    bf16x8 pf[4], vf[2];
#pragma unroll
    for (int mi = 0; mi < 4; ++mi)
      pf[mi] = *(const bf16x8*)(Ps + (mi * 16 + l15) * 72 + kt * 32 + quad * 8);
#pragma unroll
    for (int ni = 0; ni < 2; ++ni)
      vf[ni] = *(const bf16x8*)(VT + (ni * 16 + l15) * 72 + kt * 32 + quad * 8);
#pragma unroll
    for (int mi = 0; mi < 4; ++mi)
#pragma unroll
      for (int ni = 0; ni < 2; ++ni)
        O[mi][ni] = __builtin_amdgcn_mfma_f32_16x16x32_bf16(pf[mi], vf[ni], O[mi][ni], 0, 0, 0);
  }

  // write out: token-major [tok][256]
  const int b = win >> 6, wh = (win >> 3) & 7, wwd = win & 7;
#pragma unroll
  for (int mi = 0; mi < 4; ++mi) {
#pragma unroll
    for (int r = 0; r < 4; ++r) {
      const int m = mi * 16 + quad * 4 + r;
      if (m < 49) {
        const int r7 = m / 7, c7 = m % 7;
        const int tok = b * 3136 + (wh * 7 + r7) * 56 + (wwd * 7 + c7);
        bf16* op = out + (size_t)tok * 256 + head * 32;
#pragma unroll
        for (int ni = 0; ni < 2; ++ni)
          op[ni * 16 + l15] = __float2bfloat16(O[mi][ni][r]);
      }
    }
  }
}

// ---------------- launch ----------------
extern "C" void kernel_launch(void* const* d_in, const int* in_sizes, int n_in,
                              void* d_out, int out_size, void* d_ws, size_t ws_size,
                              hipStream_t stream)
{
  const float* x      = (const float*)d_in[0];
  const float* n1g    = (const float*)d_in[1];
  const float* n1b    = (const float*)d_in[2];
  const float* qkv_w  = (const float*)d_in[3];
  const float* qkv_b  = (const float*)d_in[4];
  const float* proj_w = (const float*)d_in[5];
  const float* proj_b = (const float*)d_in[6];
  const float* pp_w   = (const float*)d_in[7];
  const float* pp_b   = (const float*)d_in[8];
  const float* p1g    = (const float*)d_in[9];
  const float* p1lb   = (const float*)d_in[10];
  const float* p1w    = (const float*)d_in[11];
  const float* p1b    = (const float*)d_in[12];
  const float* p2g    = (const float*)d_in[13];
  const float* p2lb   = (const float*)d_in[14];
  const float* p2w    = (const float*)d_in[15];
  const float* p2b    = (const float*)d_in[16];
  const float* p3g    = (const float*)d_in[17];
  const float* p3lb   = (const float*)d_in[18];
  const float* p3w    = (const float*)d_in[19];
  const float* p3b    = (const float*)d_in[20];
  const float* n2g    = (const float*)d_in[21];
  const float* n2b    = (const float*)d_in[22];
  const float* fc1_w  = (const float*)d_in[23];
  const float* fc1_b  = (const float*)d_in[24];
  const float* fc2_w  = (const float*)d_in[25];
  const float* fc2_b  = (const float*)d_in[26];

  const size_t REG = (size_t)NTOK * 256 * 2;   // 51,380,224
  char* ws = (char*)d_ws;
  float* rel_bias = (float*)ws;
  bf16* wqkvT = (bf16*)(ws + 131072);
  bf16* wprojT = wqkvT + 196608;
  bf16* wfc1T = wprojT + 65536;
  bf16* wfc2T = wfc1T + 262144;
  char* R1 = ws + (2 << 20);
  char* R2 = R1 + REG;
  char* R3 = R2 + REG;
  char* R4 = R3 + REG;

  bf16*  xn   = (bf16*)R1;        // phase 1
  bf16*  qb   = (bf16*)R2;
  bf16*  kb   = (bf16*)R3;
  bf16*  vb   = (bf16*)R4;
  bf16*  aout = (bf16*)R1;        // phase 2 (xn dead)
  float* xr   = (float*)R2;       // phase 3 (q,k dead) — spans R2+R3
  bf16*  yn   = (bf16*)R4;        // phase 4 (v dead)
  bf16*  Hc   = (bf16*)R1;        // phase 5 (aout dead) — per-M-chunk hidden

  cvt_t_kernel<<<(196608 + 255) / 256, 256, 0, stream>>>(qkv_w, wqkvT, 256, 768);
  cvt_t_kernel<<<(65536 + 255) / 256, 256, 0, stream>>>(proj_w, wprojT, 256, 256);
  cvt_t_kernel<<<(262144 + 255) / 256, 256, 0, stream>>>(fc1_w, wfc1T, 256, 1024);
  cvt_t_kernel<<<(262144 + 255) / 256, 256, 0, stream>>>(fc2_w, wfc2T, 1024, 256);

  pos_kernel<<<1, 256, 0, stream>>>(pp_w, pp_b, p1g, p1lb, p1w, p1b,
                                    p2g, p2lb, p2w, p2b, p3g, p3lb, p3w, p3b, rel_bias);
  ln_wave<<<NTOK / 4, 256, 0, stream>>>(x, n1g, n1b, xn);
  gemm_mfma<0><<<dim3(NTOK / 128, 6), 256, 0, stream>>>(xn, wqkvT, qkv_b, nullptr,
      nullptr, nullptr, qb, kb, vb, NTOK, 768, 256);
  attn_mfma<<<16384, 64, 0, stream>>>(qb, kb, vb, rel_bias, aout);
  gemm_mfma<1><<<dim3(NTOK / 128, 2), 256, 0, stream>>>(aout, wprojT, proj_b, x,
      xr, nullptr, nullptr, nullptr, nullptr, NTOK, 256, 256);
  ln_wave<<<NTOK / 4, 256, 0, stream>>>(xr, n2g, n2b, yn);

  const int MC = 25088;
  for (int c = 0; c < 4; ++c) {
    const size_t mb = (size_t)c * MC;
    gemm_mfma<2><<<dim3(MC / 128, 8), 256, 0, stream>>>(yn + mb * 256, wfc1T,
        fc1_b, nullptr, nullptr, Hc, nullptr, nullptr, nullptr, MC, 1024, 256);
    gemm_mfma<5><<<dim3(MC / 128, 2), 256, 0, stream>>>(Hc, wfc2T,
        fc2_b, xr + mb * 256, (float*)d_out + mb * 256, nullptr, nullptr, nullptr, nullptr,
        MC, 256, 1024);
  }
}

// Round 6
// 740.492 us; speedup vs baseline: 3.5845x; 1.0571x over previous
//
#include <hip/hip_runtime.h>
#include <hip/hip_bf16.h>
#include <math.h>

typedef __hip_bfloat16 bf16;
typedef unsigned short u16;
typedef unsigned int   u32;
typedef __bf16  bf16x8 __attribute__((ext_vector_type(8)));
typedef float   f32x4  __attribute__((ext_vector_type(4)));

#define NTOK 100352   // 32 * 56 * 56
#define QSCALE 0.17677669529663687f

// ---------------- merged fp32 -> bf16 transposes (weights, every launch) ----
// qkv [256][768] -> [768][256]; proj [256][256] -> [256][256];
// fc1 [256][1024] -> [1024][256]; fc2 [1024][256] -> [256][1024]
__global__ __launch_bounds__(256)
void cvt_all(const float* __restrict__ qkv_w, const float* __restrict__ proj_w,
             const float* __restrict__ fc1_w, const float* __restrict__ fc2_w,
             bf16* __restrict__ wqkvT, bf16* __restrict__ wprojT,
             bf16* __restrict__ wfc1T, bf16* __restrict__ wfc2T)
{
  const int i = blockIdx.x * 256 + threadIdx.x;
  if (i < 196608) {
    const int k = i / 768, n = i % 768;
    wqkvT[n * 256 + k] = __float2bfloat16(qkv_w[i]);
  } else if (i < 262144) {
    const int j = i - 196608, k = j / 256, n = j % 256;
    wprojT[n * 256 + k] = __float2bfloat16(proj_w[j]);
  } else if (i < 524288) {
    const int j = i - 262144, k = j / 1024, n = j % 1024;
    wfc1T[n * 256 + k] = __float2bfloat16(fc1_w[j]);
  } else {
    const int j = i - 524288, k = j / 256, n = j % 256;
    wfc2T[n * 1024 + k] = __float2bfloat16(fc2_w[j]);
  }
}

// ---------------- pos-bias MLP + rel_bias table (1 block) ----------------
__device__ __forceinline__ void ln16_relu(float* cur, const float* g, const float* b) {
  float mu = 0.f;
#pragma unroll
  for (int j = 0; j < 16; ++j) mu += cur[j];
  mu *= (1.f / 16.f);
  float var = 0.f;
#pragma unroll
  for (int j = 0; j < 16; ++j) { float d = cur[j] - mu; var += d * d; }
  var *= (1.f / 16.f);
  const float r = rsqrtf(var + 1e-5f);
#pragma unroll
  for (int j = 0; j < 16; ++j) {
    float y = (cur[j] - mu) * r * g[j] + b[j];
    cur[j] = fmaxf(y, 0.f);
  }
}

__global__ __launch_bounds__(256)
void pos_kernel(const float* __restrict__ ppw, const float* __restrict__ ppb,
                const float* __restrict__ g1, const float* __restrict__ lb1,
                const float* __restrict__ w1, const float* __restrict__ b1,
                const float* __restrict__ g2, const float* __restrict__ lb2,
                const float* __restrict__ w2, const float* __restrict__ b2,
                const float* __restrict__ g3, const float* __restrict__ lb3,
                const float* __restrict__ w3, const float* __restrict__ b3,
                float* __restrict__ rel_bias)
{
  __shared__ float pos_s[169 * 8];
  const int t = threadIdx.x;
  if (t < 169) {
    float cur[16], nxt[16];
    const float bh = (float)(t / 13 - 6), bw = (float)(t % 13 - 6);
#pragma unroll
    for (int j = 0; j < 16; ++j)
      cur[j] = bh * ppw[j] + bw * ppw[16 + j] + ppb[j];
    ln16_relu(cur, g1, lb1);
    for (int j = 0; j < 16; ++j) nxt[j] = b1[j];
    for (int k = 0; k < 16; ++k) { float a = cur[k]; for (int j = 0; j < 16; ++j) nxt[j] += a * w1[k * 16 + j]; }
    for (int j = 0; j < 16; ++j) cur[j] = nxt[j];
    ln16_relu(cur, g2, lb2);
    for (int j = 0; j < 16; ++j) nxt[j] = b2[j];
    for (int k = 0; k < 16; ++k) { float a = cur[k]; for (int j = 0; j < 16; ++j) nxt[j] += a * w2[k * 16 + j]; }
    for (int j = 0; j < 16; ++j) cur[j] = nxt[j];
    ln16_relu(cur, g3, lb3);
    for (int h = 0; h < 8; ++h) {
      float s = b3[h];
      for (int k = 0; k < 16; ++k) s += cur[k] * w3[k * 8 + h];
      pos_s[t * 8 + h] = s;
    }
  }
  __syncthreads();
  for (int e = t; e < 8 * 2401; e += 256) {
    const int h = e / 2401, ij = e % 2401, i = ij / 49, j = ij % 49;
    const int dh = i / 7 - j / 7 + 6, dw = i % 7 - j % 7 + 6;
    rel_bias[e] = pos_s[(dh * 13 + dw) * 8 + h];
  }
}

// ---------------- LayerNorm over C=256: one wave per token ----------------
__global__ __launch_bounds__(256)
void ln_wave(const float* __restrict__ xin,
             const float* __restrict__ g, const float* __restrict__ b,
             bf16* __restrict__ out)
{
  const int tok = blockIdx.x * 4 + (threadIdx.x >> 6);
  const int lane = threadIdx.x & 63;
  const float4 xv = *reinterpret_cast<const float4*>(xin + (size_t)tok * 256 + lane * 4);
  float s = xv.x + xv.y + xv.z + xv.w;
#pragma unroll
  for (int off = 1; off < 64; off <<= 1) s += __shfl_xor(s, off, 64);
  const float mu = s * (1.f / 256.f);
  const float4 dx = make_float4(xv.x - mu, xv.y - mu, xv.z - mu, xv.w - mu);
  float v = dx.x * dx.x + dx.y * dx.y + dx.z * dx.z + dx.w * dx.w;
#pragma unroll
  for (int off = 1; off < 64; off <<= 1) v += __shfl_xor(v, off, 64);
  const float rstd = rsqrtf(v * (1.f / 256.f) + 1e-5f);
  const float4 gv = *reinterpret_cast<const float4*>(g + lane * 4);
  const float4 bv = *reinterpret_cast<const float4*>(b + lane * 4);
  bf16 o0 = __float2bfloat16(dx.x * rstd * gv.x + bv.x);
  bf16 o1 = __float2bfloat16(dx.y * rstd * gv.y + bv.y);
  bf16 o2 = __float2bfloat16(dx.z * rstd * gv.z + bv.z);
  bf16 o3 = __float2bfloat16(dx.w * rstd * gv.w + bv.w);
  ushort4 st = make_ushort4(*(u16*)&o0, *(u16*)&o1, *(u16*)&o2, *(u16*)&o3);
  *reinterpret_cast<ushort4*>(out + (size_t)tok * 256 + lane * 4) = st;
}

// ---------------- MFMA GEMM: C[M,N] = A[M,K] @ BT[N,K]^T + epilogue ------
template<int EPI>
__global__ __launch_bounds__(256, 2)
void gemm_mfma(const bf16* __restrict__ A, const bf16* __restrict__ BT,
               const float* __restrict__ bias, const float* __restrict__ resF,
               float* __restrict__ outF, bf16* __restrict__ outB,
               bf16* __restrict__ outQ, bf16* __restrict__ outK, bf16* __restrict__ outV,
               const int M, const int N, const int K)
{
  __shared__ __align__(16) u16 Alds[128 * 32];
  __shared__ __align__(16) u16 Blds[128 * 32];
  const int t = threadIdx.x;
  const int m0 = blockIdx.x << 7, n0 = blockIdx.y << 7;
  const int wave = t >> 6, lane = t & 63;
  const int quad = lane >> 4, l15 = lane & 15;
  const int mw = (wave & 1) << 6, nw = (wave >> 1) << 6;

  const int sr = t >> 2, sc = (t & 3) << 3;
  const bf16* ag0 = A  + (size_t)(m0 + sr) * K + sc;
  const bf16* ag1 = ag0 + (size_t)64 * K;
  const bf16* bg0 = BT + (size_t)(n0 + sr) * K + sc;
  const bf16* bg1 = bg0 + (size_t)64 * K;
  char* alds0 = (char*)Alds + t * 16;
  char* alds1 = (char*)Alds + 4096 + t * 16;
  char* blds0 = (char*)Blds + t * 16;
  char* blds1 = (char*)Blds + 4096 + t * 16;

  f32x4 acc[4][4];
#pragma unroll
  for (int mi = 0; mi < 4; ++mi)
#pragma unroll
    for (int ni = 0; ni < 4; ++ni) acc[mi][ni] = (f32x4){0.f, 0.f, 0.f, 0.f};

  for (int kt = 0; kt < K; kt += 32) {
    __builtin_amdgcn_global_load_lds((const __attribute__((address_space(1))) void*)(ag0 + kt),
        (__attribute__((address_space(3))) void*)alds0, 16, 0, 0);
    __builtin_amdgcn_global_load_lds((const __attribute__((address_space(1))) void*)(ag1 + kt),
        (__attribute__((address_space(3))) void*)alds1, 16, 0, 0);
    __builtin_amdgcn_global_load_lds((const __attribute__((address_space(1))) void*)(bg0 + kt),
        (__attribute__((address_space(3))) void*)blds0, 16, 0, 0);
    __builtin_amdgcn_global_load_lds((const __attribute__((address_space(1))) void*)(bg1 + kt),
        (__attribute__((address_space(3))) void*)blds1, 16, 0, 0);
    __syncthreads();

    bf16x8 af[4], bfr[4];
#pragma unroll
    for (int mi = 0; mi < 4; ++mi)
      af[mi] = *(const bf16x8*)(Alds + (mw + mi * 16 + l15) * 32 + quad * 8);
#pragma unroll
    for (int ni = 0; ni < 4; ++ni)
      bfr[ni] = *(const bf16x8*)(Blds + (nw + ni * 16 + l15) * 32 + quad * 8);
#pragma unroll
    for (int mi = 0; mi < 4; ++mi)
#pragma unroll
      for (int ni = 0; ni < 4; ++ni)
        acc[mi][ni] = __builtin_amdgcn_mfma_f32_16x16x32_bf16(af[mi], bfr[ni], acc[mi][ni], 0, 0, 0);
    __syncthreads();
  }

#pragma unroll
  for (int mi = 0; mi < 4; ++mi) {
#pragma unroll
    for (int r = 0; r < 4; ++r) {
      const int m = m0 + mw + mi * 16 + quad * 4 + r;
      if (EPI == 0) {
        const int bb = m / 3136, l = m % 3136;
        const int hh = l / 56, ww = l % 56;
        const int win = bb * 64 + (hh / 7) * 8 + (ww / 7);
        const int p = (hh % 7) * 7 + (ww % 7);
        const size_t tokbase = ((size_t)win * 8) * 1568 + (size_t)p * 32;
#pragma unroll
        for (int ni = 0; ni < 4; ++ni) {
          const int n = n0 + nw + ni * 16 + l15;
          const float val = acc[mi][ni][r] + bias[n];
          const int which = n >> 8, head = (n >> 5) & 7, d = n & 31;
          const size_t idx = tokbase + (size_t)head * 1568 + d;
          if (which == 0)      outQ[idx] = __float2bfloat16(val * QSCALE);
          else if (which == 1) outK[idx] = __float2bfloat16(val);
          else                 outV[idx] = __float2bfloat16(val);
        }
      } else if (EPI == 1) {
#pragma unroll
        for (int ni = 0; ni < 4; ++ni) {
          const int n = n0 + nw + ni * 16 + l15;
          outF[(size_t)m * N + n] = acc[mi][ni][r] + bias[n] + resF[(size_t)m * N + n];
        }
      } else if (EPI == 2) {
#pragma unroll
        for (int ni = 0; ni < 4; ++ni) {
          const int n = n0 + nw + ni * 16 + l15;
          const float z = acc[mi][ni][r] + bias[n];
          const float ge = 0.5f * z * (1.f + erff(z * 0.7071067811865476f));
          outB[(size_t)m * N + n] = __float2bfloat16(ge);
        }
      } else {
#pragma unroll
        for (int ni = 0; ni < 4; ++ni) {
          const int n = n0 + nw + ni * 16 + l15;
          outF[(size_t)m * N + n] = resF[(size_t)m * N + n] + acc[mi][ni][r] + bias[n];
        }
      }
    }
  }
}

// ---------------- MFMA attention v2: one wave per (window, head) ------------
// No Q/K/V LDS staging: fragments loaded directly from global (coalesced for
// Q/K; V via small strided loads). Rows/cols >= 49 clamped to stay in-slice;
// S cols >= 49 masked to -3e38 so softmax P[:, j>=49] == 0 exactly, which
// annihilates V garbage in PV. Only the P C->A layout round-trip uses LDS.
__global__ __launch_bounds__(64)
void attn_mfma(const bf16* __restrict__ q, const bf16* __restrict__ k,
               const bf16* __restrict__ v, const float* __restrict__ rel_bias,
               bf16* __restrict__ out)
{
  __shared__ __align__(16) u16 Ps[64 * 72];
  const int bid = blockIdx.x;           // win*8 + head
  const int win = bid >> 3, head = bid & 7;
  const int lane = threadIdx.x;
  const int quad = lane >> 4, l15 = lane & 15;
  const size_t base = (size_t)bid * 1568;

  // Q/K fragments straight from global: lane reads 16B at row (clamped), col quad*8
  bf16x8 qf[4], kf[4];
#pragma unroll
  for (int mi = 0; mi < 4; ++mi) {
    const int rr = mi * 16 + l15;
    const int rc = rr < 49 ? rr : 48;
    qf[mi] = *(const bf16x8*)(q + base + rc * 32 + quad * 8);
    kf[mi] = *(const bf16x8*)(k + base + rc * 32 + quad * 8);
  }

  f32x4 S[4][4];
#pragma unroll
  for (int mi = 0; mi < 4; ++mi)
#pragma unroll
    for (int ni = 0; ni < 4; ++ni)
      S[mi][ni] = __builtin_amdgcn_mfma_f32_16x16x32_bf16(qf[mi], kf[ni],
                                                          (f32x4){0.f, 0.f, 0.f, 0.f}, 0, 0, 0);

  // V B-fragments: vf[kt][ni][jj] = V[kt*32+quad*8+jj][ni*16+l15] (row clamped)
  u16 vtmp[2][2][8];
#pragma unroll
  for (int kt = 0; kt < 2; ++kt)
#pragma unroll
    for (int jj = 0; jj < 8; ++jj) {
      const int row = kt * 32 + quad * 8 + jj;
      const int rc = row < 49 ? row : 48;
#pragma unroll
      for (int ni = 0; ni < 2; ++ni)
        vtmp[kt][ni][jj] = *(const u16*)(v + base + rc * 32 + ni * 16 + l15);
    }

  // bias + mask + row softmax (row = quad*4+r, col = l15 across 16 lanes)
  const float* rb = rel_bias + head * 2401;
#pragma unroll
  for (int mi = 0; mi < 4; ++mi) {
#pragma unroll
    for (int r = 0; r < 4; ++r) {
      const int m = mi * 16 + quad * 4 + r;
      const int mc = m < 49 ? m : 48;
      float sv[4];
#pragma unroll
      for (int ni = 0; ni < 4; ++ni) {
        const int n = ni * 16 + l15;
        sv[ni] = (n < 49) ? (S[mi][ni][r] + rb[mc * 49 + n]) : -3e38f;
      }
      float mx = fmaxf(fmaxf(sv[0], sv[1]), fmaxf(sv[2], sv[3]));
#pragma unroll
      for (int off = 1; off < 16; off <<= 1) mx = fmaxf(mx, __shfl_xor(mx, off, 64));
      float sum = 0.f;
#pragma unroll
      for (int ni = 0; ni < 4; ++ni) { sv[ni] = __expf(sv[ni] - mx); sum += sv[ni]; }
#pragma unroll
      for (int off = 1; off < 16; off <<= 1) sum += __shfl_xor(sum, off, 64);
      const float inv = 1.f / sum;
#pragma unroll
      for (int ni = 0; ni < 4; ++ni) S[mi][ni][r] = sv[ni] * inv;
    }
  }

  // P -> LDS in A-operand layout [m][j], ld=72
#pragma unroll
  for (int mi = 0; mi < 4; ++mi)
#pragma unroll
    for (int r = 0; r < 4; ++r) {
      const int m = mi * 16 + quad * 4 + r;
#pragma unroll
      for (int ni = 0; ni < 4; ++ni) {
        const bf16 pb = __float2bfloat16(S[mi][ni][r]);
        Ps[m * 72 + ni * 16 + l15] = *(const u16*)&pb;
      }
    }
  __syncthreads();

  // O = P @ V : A = P [64 x 64j], B = V^T [32d x 64j] -> O [64 x 32]
  f32x4 O[4][2];
#pragma unroll
  for (int mi = 0; mi < 4; ++mi)
#pragma unroll
    for (int ni = 0; ni < 2; ++ni) O[mi][ni] = (f32x4){0.f, 0.f, 0.f, 0.f};
#pragma unroll
  for (int kt = 0; kt < 2; ++kt) {
    bf16x8 pf[4];
#pragma unroll
    for (int mi = 0; mi < 4; ++mi)
      pf[mi] = *(const bf16x8*)(Ps + (mi * 16 + l15) * 72 + kt * 32 + quad * 8);
#pragma unroll
    for (int ni = 0; ni < 2; ++ni) {
      bf16x8 vf = *(const bf16x8*)&vtmp[kt][ni][0];
#pragma unroll
      for (int mi = 0; mi < 4; ++mi)
        O[mi][ni] = __builtin_amdgcn_mfma_f32_16x16x32_bf16(pf[mi], vf, O[mi][ni], 0, 0, 0);
    }
  }

  // write out token-major [tok][256]
  const int b = win >> 6, wh = (win >> 3) & 7, wwd = win & 7;
#pragma unroll
  for (int mi = 0; mi < 4; ++mi) {
#pragma unroll
    for (int r = 0; r < 4; ++r) {
      const int m = mi * 16 + quad * 4 + r;
      if (m < 49) {
        const int r7 = m / 7, c7 = m % 7;
        const int tok = b * 3136 + (wh * 7 + r7) * 56 + (wwd * 7 + c7);
        bf16* op = out + (size_t)tok * 256 + head * 32;
#pragma unroll
        for (int ni = 0; ni < 2; ++ni)
          op[ni * 16 + l15] = __float2bfloat16(O[mi][ni][r]);
      }
    }
  }
}

// ---------------- launch ----------------
// Workspace (~207 MB):
//   [0, 128KB)   rel_bias
//   [128KB, 2MB) bf16 transposed weights
//   R1..R4 (REG = NTOK*256*2 each): R1: xn -> aout; R2,R3: q,k -> Hc (MLP
//   hidden, 2 chunks of 50176 tokens); R4: v -> yn.
//   fp32 residual xr lives in d_out itself (proj writes, LN2 reads, FC2
//   reads+rewrites elementwise).
extern "C" void kernel_launch(void* const* d_in, const int* in_sizes, int n_in,
                              void* d_out, int out_size, void* d_ws, size_t ws_size,
                              hipStream_t stream)
{
  const float* x      = (const float*)d_in[0];
  const float* n1g    = (const float*)d_in[1];
  const float* n1b    = (const float*)d_in[2];
  const float* qkv_w  = (const float*)d_in[3];
  const float* qkv_b  = (const float*)d_in[4];
  const float* proj_w = (const float*)d_in[5];
  const float* proj_b = (const float*)d_in[6];
  const float* pp_w   = (const float*)d_in[7];
  const float* pp_b   = (const float*)d_in[8];
  const float* p1g    = (const float*)d_in[9];
  const float* p1lb   = (const float*)d_in[10];
  const float* p1w    = (const float*)d_in[11];
  const float* p1b    = (const float*)d_in[12];
  const float* p2g    = (const float*)d_in[13];
  const float* p2lb   = (const float*)d_in[14];
  const float* p2w    = (const float*)d_in[15];
  const float* p2b    = (const float*)d_in[16];
  const float* p3g    = (const float*)d_in[17];
  const float* p3lb   = (const float*)d_in[18];
  const float* p3w    = (const float*)d_in[19];
  const float* p3b    = (const float*)d_in[20];
  const float* n2g    = (const float*)d_in[21];
  const float* n2b    = (const float*)d_in[22];
  const float* fc1_w  = (const float*)d_in[23];
  const float* fc1_b  = (const float*)d_in[24];
  const float* fc2_w  = (const float*)d_in[25];
  const float* fc2_b  = (const float*)d_in[26];

  const size_t REG = (size_t)NTOK * 256 * 2;   // 51,380,224
  char* ws = (char*)d_ws;
  float* rel_bias = (float*)ws;
  bf16* wqkvT = (bf16*)(ws + 131072);
  bf16* wprojT = wqkvT + 196608;
  bf16* wfc1T = wprojT + 65536;
  bf16* wfc2T = wfc1T + 262144;
  char* R1 = ws + (2 << 20);
  char* R2 = R1 + REG;
  char* R3 = R2 + REG;
  char* R4 = R3 + REG;

  bf16*  xn   = (bf16*)R1;        // phase 1
  bf16*  qb   = (bf16*)R2;
  bf16*  kb   = (bf16*)R3;
  bf16*  vb   = (bf16*)R4;
  bf16*  aout = (bf16*)R1;        // phase 2 (xn dead)
  float* xr   = (float*)d_out;    // fp32 residual in the output buffer
  bf16*  yn   = (bf16*)R4;        // phase 4 (v dead)
  bf16*  Hc   = (bf16*)R2;        // phase 5 (q,k dead) — spans R2+R3

  cvt_all<<<3072, 256, 0, stream>>>(qkv_w, proj_w, fc1_w, fc2_w,
                                    wqkvT, wprojT, wfc1T, wfc2T);
  pos_kernel<<<1, 256, 0, stream>>>(pp_w, pp_b, p1g, p1lb, p1w, p1b,
                                    p2g, p2lb, p2w, p2b, p3g, p3lb, p3w, p3b, rel_bias);
  ln_wave<<<NTOK / 4, 256, 0, stream>>>(x, n1g, n1b, xn);
  gemm_mfma<0><<<dim3(NTOK / 128, 6), 256, 0, stream>>>(xn, wqkvT, qkv_b, nullptr,
      nullptr, nullptr, qb, kb, vb, NTOK, 768, 256);
  attn_mfma<<<16384, 64, 0, stream>>>(qb, kb, vb, rel_bias, aout);
  gemm_mfma<1><<<dim3(NTOK / 128, 2), 256, 0, stream>>>(aout, wprojT, proj_b, x,
      xr, nullptr, nullptr, nullptr, nullptr, NTOK, 256, 256);
  ln_wave<<<NTOK / 4, 256, 0, stream>>>(xr, n2g, n2b, yn);

  // MLP in 2 M-chunks of 50176 tokens (hidden chunk = R2+R3):
  const int MC = 50176;
  for (int c = 0; c < 2; ++c) {
    const size_t mb = (size_t)c * MC;
    gemm_mfma<2><<<dim3(MC / 128, 8), 256, 0, stream>>>(yn + mb * 256, wfc1T,
        fc1_b, nullptr, nullptr, Hc, nullptr, nullptr, nullptr, MC, 1024, 256);
    gemm_mfma<5><<<dim3(MC / 128, 2), 256, 0, stream>>>(Hc, wfc2T,
        fc2_b, xr + mb * 256, xr + mb * 256, nullptr, nullptr, nullptr, nullptr,
        MC, 256, 1024);
  }
}